// Round 4
// baseline (10833.964 us; speedup 1.0000x reference)
//
#include <hip/hip_runtime.h>
#include <hip/hip_bf16.h>

// Problem constants
#define SEQ  256
#define BSZ  128
#define DM   512
#define HID  1536
#define KTOT 2560      // x(512) | r(512) | h(1536)
#define VC   6144      // virtual cols: [0,3072) fused rz, [3072,4608) inn, [4608,6144) hn

typedef __attribute__((ext_vector_type(4))) float f32x4;
typedef __attribute__((ext_vector_type(8))) short short8;
typedef __attribute__((ext_vector_type(4))) unsigned short us4;
typedef __attribute__((ext_vector_type(8))) unsigned short us8;

// ws layout (bytes)
#define OFF_WBH 0ull                 // bf16 [4608][2560] hi   = 23,592,960
#define OFF_WBL 23592960ull          // bf16 [4608][2560] lo   = 23,592,960
#define OFF_P   47185920ull          // f32  [5][128][6144]    = 15,728,640
#define OFF_R32 62914560ull          // f32  [128][512]        =    262,144
#define OFF_A   63176704ull          // f32  [1024][64][64]    = 16,777,216   (zeroed)
#define OFF_H32 79953920ull          // f32  [128][1536]       =    786,432   (zeroed)
#define OFF_RBH 80740352ull          // bf16 [128][512]  hi    =    131,072   (zeroed)
#define OFF_RBL 80871424ull          // bf16 [128][512]  lo    =    131,072   (zeroed)
#define OFF_HBH 81002496ull          // bf16 [128][1536] hi    =    393,216   (zeroed)
#define OFF_HBL 81395712ull          // bf16 [128][1536] lo    =    393,216   (zeroed)
// zero region: OFF_A .. 81,788,928  -> 18,612,224 B = 1,163,264 x 16B = 4544 blocks x 256

static __device__ __forceinline__ unsigned short bf(float x) {
  __hip_bfloat16 h = __float2bfloat16(x);
  return *reinterpret_cast<unsigned short*>(&h);
}
static __device__ __forceinline__ float bf2f(unsigned short u) {
  union { unsigned int i; float f; } c; c.i = ((unsigned int)u) << 16;
  return c.f;
}

// ---------------- prep: repack weights to hi/lo bf16 [4608][2560] ----------------
__global__ __launch_bounds__(256) void pk_wb(const float* __restrict__ Wih,
                                             const float* __restrict__ Whh,
                                             unsigned short* __restrict__ Wh,
                                             unsigned short* __restrict__ Wl) {
  int idx = blockIdx.x * 256 + threadIdx.x;        // < 4608*640 = 2,949,120
  int row = idx / 640;
  int k = (idx - row * 640) * 4;
  const float* src = (k < 1024) ? (Wih + (size_t)row * 1024 + k)
                                : (Whh + (size_t)row * HID + (k - 1024));
  f32x4 v = *(const f32x4*)src;
  us4 oh, ol;
#pragma unroll
  for (int i = 0; i < 4; ++i) {
    unsigned short h = bf(v[i]);
    oh[i] = h;
    ol[i] = bf(v[i] - bf2f(h));
  }
  *(us4*)(Wh + (size_t)row * KTOT + k) = oh;
  *(us4*)(Wl + (size_t)row * KTOT + k) = ol;
}

// ---------------- prep: zero A, h32, Rb*, Hb* (contiguous region) ----------------
__global__ __launch_bounds__(256) void pk_zero(f32x4* __restrict__ dst) {
  f32x4 z = {0.f, 0.f, 0.f, 0.f};
  dst[(size_t)blockIdx.x * 256 + threadIdx.x] = z;
}

// ---------------- per-step fused GEMM (hi/lo 3-term): P[ks][b][vcol] ----------------
// grid 480 = 96 jgroups x 5 ksplits; block 256 = 4 waves; tile [128b x 64vcol], K-chunk 512
__global__ __launch_bounds__(256) void gemm_step(
    int t, const float* __restrict__ x,
    const unsigned short* __restrict__ Rbh, const unsigned short* __restrict__ Rbl,
    const unsigned short* __restrict__ Hbh, const unsigned short* __restrict__ Hbl,
    const unsigned short* __restrict__ Wh,  const unsigned short* __restrict__ Wl,
    float* __restrict__ P)
{
  int jg = blockIdx.x % 96;
  int ks = blockIdx.x / 96;                 // 0..4, K chunk [ks*512, ks*512+512)
  int klo, khi;
  if (jg < 48)      { klo = 0;    khi = 2560; }   // fused rz rows, full K
  else if (jg < 72) { klo = 0;    khi = 1024; }   // inn rows: xr part only
  else              { klo = 1024; khi = 2560; }   // hn rows: h part only
  int kc0 = ks * 512;
  if (kc0 < klo || kc0 + 512 > khi) return;

  __shared__ __align__(16) unsigned short AH[128 * 40];   // [128][32] +8 pad
  __shared__ __align__(16) unsigned short AL[128 * 40];

  int tid  = threadIdx.x;
  int wave = tid >> 6, lane = tid & 63;
  int bh = (wave & 1) * 64;                  // b-half base (0 or 64)
  int jh = (wave >> 1) * 32;                 // j-half base within 64 (0 or 32)
  int l15 = lane & 15, kg = lane >> 4;

  // virtual col -> W row (inn/hn share W rows [3072,4608))
  int wrow0 = (jg < 72 ? jg * 64 : jg * 64 - 1536) + jh;

  f32x4 acc[4][2];
#pragma unroll
  for (int i = 0; i < 4; ++i)
#pragma unroll
    for (int j = 0; j < 2; ++j) acc[i][j] = (f32x4){0.f, 0.f, 0.f, 0.f};

  int r = tid >> 1;            // staging row 0..127
  int hc = (tid & 1) * 16;     // staging col 0 or 16

  for (int it = 0; it < 16; ++it) {
    int kabs = kc0 + it * 32;
    us8 h0, h1, l0, l1;
    if (ks == 0) {             // chunk [0,512): x (f32 -> hi/lo bf16)
      const float* p = x + ((size_t)t * BSZ + r) * DM + kabs + hc;
      f32x4 f[4];
      f[0] = *(const f32x4*)(p);
      f[1] = *(const f32x4*)(p + 4);
      f[2] = *(const f32x4*)(p + 8);
      f[3] = *(const f32x4*)(p + 12);
#pragma unroll
      for (int g = 0; g < 2; ++g)
#pragma unroll
        for (int i = 0; i < 4; ++i) {
          float xv = f[g][i];
          unsigned short hh = bf(xv);
          h0[g * 4 + i] = hh; l0[g * 4 + i] = bf(xv - bf2f(hh));
        }
#pragma unroll
      for (int g = 2; g < 4; ++g)
#pragma unroll
        for (int i = 0; i < 4; ++i) {
          float xv = f[g][i];
          unsigned short hh = bf(xv);
          h1[(g - 2) * 4 + i] = hh; l1[(g - 2) * 4 + i] = bf(xv - bf2f(hh));
        }
    } else if (ks == 1) {      // chunk [512,1024): r (bf16 hi/lo)
      size_t off = (size_t)r * DM + (kabs - 512) + hc;
      h0 = *(const us8*)(Rbh + off); h1 = *(const us8*)(Rbh + off + 8);
      l0 = *(const us8*)(Rbl + off); l1 = *(const us8*)(Rbl + off + 8);
    } else {                   // chunks [1024,2560): h (bf16 hi/lo)
      size_t off = (size_t)r * HID + (kabs - 1024) + hc;
      h0 = *(const us8*)(Hbh + off); h1 = *(const us8*)(Hbh + off + 8);
      l0 = *(const us8*)(Hbl + off); l1 = *(const us8*)(Hbl + off + 8);
    }
    __syncthreads();
    *(us8*)&AH[r * 40 + hc]     = h0;
    *(us8*)&AH[r * 40 + hc + 8] = h1;
    *(us8*)&AL[r * 40 + hc]     = l0;
    *(us8*)&AL[r * 40 + hc + 8] = l1;
    __syncthreads();

    short8 bh_[2], bl_[2];
#pragma unroll
    for (int jt = 0; jt < 2; ++jt) {
      size_t woff = (size_t)(wrow0 + jt * 16 + l15) * KTOT + kabs + kg * 8;
      bh_[jt] = *(const short8*)(Wh + woff);
      bl_[jt] = *(const short8*)(Wl + woff);
    }
#pragma unroll
    for (int bt = 0; bt < 4; ++bt) {
      short8 ah = *(const short8*)&AH[(bh + bt * 16 + l15) * 40 + kg * 8];
      short8 al = *(const short8*)&AL[(bh + bt * 16 + l15) * 40 + kg * 8];
      acc[bt][0] = __builtin_amdgcn_mfma_f32_16x16x32_bf16(ah, bh_[0], acc[bt][0], 0, 0, 0);
      acc[bt][1] = __builtin_amdgcn_mfma_f32_16x16x32_bf16(ah, bh_[1], acc[bt][1], 0, 0, 0);
      acc[bt][0] = __builtin_amdgcn_mfma_f32_16x16x32_bf16(ah, bl_[0], acc[bt][0], 0, 0, 0);
      acc[bt][1] = __builtin_amdgcn_mfma_f32_16x16x32_bf16(ah, bl_[1], acc[bt][1], 0, 0, 0);
      acc[bt][0] = __builtin_amdgcn_mfma_f32_16x16x32_bf16(al, bh_[0], acc[bt][0], 0, 0, 0);
      acc[bt][1] = __builtin_amdgcn_mfma_f32_16x16x32_bf16(al, bh_[1], acc[bt][1], 0, 0, 0);
    }
  }

  int colb = jg * 64 + jh;
#pragma unroll
  for (int bt = 0; bt < 4; ++bt)
#pragma unroll
    for (int jt = 0; jt < 2; ++jt)
#pragma unroll
      for (int i = 0; i < 4; ++i) {
        int brow = bh + bt * 16 + kg * 4 + i;
        int col  = colb + jt * 16 + l15;
        P[((size_t)ks * BSZ + brow) * VC + col] = acc[bt][jt][i];
      }
}

// ---------------- per-step gates + fast-weight update ----------------
// grid 1024 (= 128 b x 8 heads), block 64 (1 wave), lane = head-dim element
__global__ __launch_bounds__(64) void pair_step(
    int t, const float* __restrict__ P, const float* __restrict__ bih,
    const float* __restrict__ bhh, float* __restrict__ A,
    float* __restrict__ h32,
    unsigned short* __restrict__ Rbh, unsigned short* __restrict__ Rbl,
    unsigned short* __restrict__ Hbh, unsigned short* __restrict__ Hbl,
    float* __restrict__ r32, float* __restrict__ dout)
{
  int pair = blockIdx.x;
  int b = pair >> 3, n = pair & 7;
  int l = threadIdx.x;
  __shared__ __align__(16) float kL[64];
  __shared__ __align__(16) float qL[64];

  const float* Pb = P + (size_t)b * VC;
  float hv[3];
#pragma unroll
  for (int s = 0; s < 3; ++s) {
    int c = s * 512 + n * 64 + l;          // h column
    float sr = 0.f, sz = 0.f;
#pragma unroll
    for (int ksi = 0; ksi < 5; ++ksi) {
      const float* q = Pb + (size_t)ksi * BSZ * VC;
      sr += q[c];
      sz += q[1536 + c];
    }
    float gin = Pb[3072 + c] + Pb[(size_t)BSZ * VC + 3072 + c];
    float ghn = 0.f;
#pragma unroll
    for (int ksi = 2; ksi < 5; ++ksi) ghn += Pb[(size_t)ksi * BSZ * VC + 4608 + c];
    float rg = 1.f / (1.f + __expf(-(sr + bih[c] + bhh[c])));
    float zg = 1.f / (1.f + __expf(-(sz + bih[1536 + c] + bhh[1536 + c])));
    float nn = tanhf(gin + bih[3072 + c] + rg * (ghn + bhh[3072 + c]));
    size_t hix = (size_t)b * HID + c;
    float hp = h32[hix];
    float hnew = (1.f - zg) * nn + zg * hp;
    h32[hix] = hnew;
    unsigned short hh = bf(hnew);
    Hbh[hix] = hh;
    Hbl[hix] = bf(hnew - bf2f(hh));
    hv[s] = hnew;
  }

  // unit norms over the 64-lane head dim
  float ssq = hv[0] * hv[0], ssk = hv[1] * hv[1];
#pragma unroll
  for (int off = 32; off > 0; off >>= 1) {
    ssq += __shfl_xor(ssq, off);
    ssk += __shfl_xor(ssk, off);
  }
  float qn = hv[0] * rsqrtf(ssq);
  float kn = hv[1] * rsqrtf(ssk);
  float ke = kn > 0.f ? kn : expm1f(kn);   // elu(unitnorm)
  kL[l] = ke;
  qL[l] = qn;
  __syncthreads();

  // A[v=l][q] += ke[q]*v[l];  r[v=l] = sum_q qn[q]*A[l][q]  (post-update, as in ref)
  float vvl = hv[2];
  float* Arow = A + ((size_t)pair * 64 + l) * 64;
  float racc = 0.f;
#pragma unroll
  for (int q4 = 0; q4 < 16; ++q4) {
    f32x4 a  = *(f32x4*)(Arow + q4 * 4);
    f32x4 kk = *(f32x4*)&kL[q4 * 4];
    f32x4 qq = *(f32x4*)&qL[q4 * 4];
    a[0] += kk[0] * vvl; a[1] += kk[1] * vvl;
    a[2] += kk[2] * vvl; a[3] += kk[3] * vvl;
    racc += qq[0] * a[0] + qq[1] * a[1] + qq[2] * a[2] + qq[3] * a[3];
    *(f32x4*)(Arow + q4 * 4) = a;
  }
  size_t ri = (size_t)b * DM + n * 64 + l;
  r32[ri] = racc;
  unsigned short rh = bf(racc);
  Rbh[ri] = rh;
  Rbl[ri] = bf(racc - bf2f(rh));

  if (t == SEQ - 1) {
    dout[65536  + pair * 64 + l] = ke;   // k output (f32)
    dout[131072 + pair * 64 + l] = qn;   // q output (f32)
  }
}

// ---------------- final: out = r @ Wo.T + bo (f32) ----------------
__global__ __launch_bounds__(512) void out_gemm(const float* __restrict__ r32,
                                                const float* __restrict__ Wo,
                                                const float* __restrict__ bo,
                                                float* __restrict__ dout) {
  int b0 = blockIdx.x * 2;
  int o  = threadIdx.x;
  __shared__ float rL0[512];
  __shared__ float rL1[512];
  rL0[o] = r32[(size_t)b0 * DM + o];
  rL1[o] = r32[(size_t)(b0 + 1) * DM + o];
  __syncthreads();
  float a0 = bo[o], a1 = a0;
  const float* wrow = Wo + (size_t)o * DM;
  for (int c = 0; c < DM; ++c) {
    float w = wrow[c];
    a0 += rL0[c] * w;
    a1 += rL1[c] * w;
  }
  dout[(size_t)b0 * DM + o]       = a0;
  dout[(size_t)(b0 + 1) * DM + o] = a1;
}

extern "C" void kernel_launch(void* const* d_in, const int* in_sizes, int n_in,
                              void* d_out, int out_size, void* d_ws, size_t ws_size,
                              hipStream_t stream) {
  // Defensive input identification by element count (deterministic).
  int ix = 0, iwih = 1, iwhh = 2, ibih = 3, ibhh = 4, iwo = 5, ibo = 6;
  {
    int b1 = -1, b2 = -1;
    for (int i = 0; i < n_in; ++i) {
      int s = in_sizes[i];
      if      (s == SEQ * BSZ * DM) ix = i;
      else if (s == 4608 * 1024)    iwih = i;
      else if (s == 4608 * 1536)    iwhh = i;
      else if (s == DM * DM)        iwo = i;
      else if (s == DM)             ibo = i;
      else if (s == 4608)           { if (b1 < 0) b1 = i; else b2 = i; }
    }
    if (b1 >= 0) ibih = b1;
    if (b2 >= 0) ibhh = b2;
  }
  const float* x   = (const float*)d_in[ix];
  const float* Wih = (const float*)d_in[iwih];
  const float* Whh = (const float*)d_in[iwhh];
  const float* bih = (const float*)d_in[ibih];
  const float* bhh = (const float*)d_in[ibhh];
  const float* Wo  = (const float*)d_in[iwo];
  const float* bo  = (const float*)d_in[ibo];

  char* ws = (char*)d_ws;
  unsigned short* Wh  = (unsigned short*)(ws + OFF_WBH);
  unsigned short* Wl  = (unsigned short*)(ws + OFF_WBL);
  float*          P   = (float*)(ws + OFF_P);
  float*          r32 = (float*)(ws + OFF_R32);
  float*          A   = (float*)(ws + OFF_A);
  float*          h32 = (float*)(ws + OFF_H32);
  unsigned short* Rbh = (unsigned short*)(ws + OFF_RBH);
  unsigned short* Rbl = (unsigned short*)(ws + OFF_RBL);
  unsigned short* Hbh = (unsigned short*)(ws + OFF_HBH);
  unsigned short* Hbl = (unsigned short*)(ws + OFF_HBL);
  float* dout = (float*)d_out;

  pk_wb  <<<11520, 256, 0, stream>>>(Wih, Whh, Wh, Wl);
  pk_zero<<<4544,  256, 0, stream>>>((f32x4*)(ws + OFF_A));

  for (int t = 0; t < SEQ; ++t) {
    gemm_step<<<480, 256, 0, stream>>>(t, x, Rbh, Rbl, Hbh, Hbl, Wh, Wl, P);
    pair_step<<<1024, 64, 0, stream>>>(t, P, bih, bhh, A, h32, Rbh, Rbl, Hbh, Hbl, r32, dout);
  }
  out_gemm<<<64, 512, 0, stream>>>(r32, Wo, bo, dout);
}